// Round 3
// baseline (739.592 us; speedup 1.0000x reference)
//
#include <hip/hip_runtime.h>
#include <hip/hip_bf16.h>

// HRR self-attention, real-arithmetic + Hermitian-packed restructure (round 6):
//   qkv = x @ [Wq;Wkv]^T  (bf16 MFMA GEMM, per-head L2-normalize fused; Parseval)
//   F   = qkv_rows(2R x 128) @ CSp^T  (packed rDFT-128 as GEMM, out 2R x 128)
//   freq-domain causal cumsum of KF + complex mult -> QV (67 MB, packed)
//   out = QV_flat @ Wo2^T  where Wo2 = Wo (.) blockdiag-iDFT  (folded on device)
// Round 6: gemm256 K-loop software-pipelined at the LDS level. Rounds 4/5 ran
// [reads -> barrier -> lgkmcnt(0) -> MFMA -> barrier] per phase: every phase
// exposes full ds_read issue+latency with the matrix pipe idle (43% MfmaUtil,
// 5212 cyc/K-tile vs m201's 3297). Now each read window feeds the NEXT
// phase's MFMA cluster (counted lgkmcnt: 12/4/8/0), so read latency hides
// under the previous cluster's MFMA window (m196's ds_read||MFMA interleave).
// A fragments split into aL/aH (+32 VGPR); staging addressing slimmed to one
// per-lane offset + uniform bases to stay within the 256-reg unified budget.

typedef unsigned short u16;
typedef unsigned int u32;
typedef __attribute__((ext_vector_type(8))) short short8;
typedef __attribute__((ext_vector_type(4))) float f32x4;

__device__ __forceinline__ float bf2f(u16 u) {
  u32 x = ((u32)u) << 16;
  float f; __builtin_memcpy(&f, &x, 4); return f;
}
__device__ __forceinline__ u16 f2bf(float f) {
  __hip_bfloat16 h = __float2bfloat16(f);
  u16 u; __builtin_memcpy(&u, &h, 2); return u;
}
__device__ __forceinline__ u32 pack2(float a, float b) {
  return (u32)f2bf(a) | ((u32)f2bf(b) << 16);
}

#define GLD16(gp, lp)                                                        \
  __builtin_amdgcn_global_load_lds(                                          \
      (const __attribute__((address_space(1))) void*)(gp),                   \
      (__attribute__((address_space(3))) void*)(lp), 16, 0, 0)

// LDS byte offset of a generic pointer derived from __shared__
__device__ __forceinline__ unsigned ldsoff(const void* p) {
  return (unsigned)(size_t)(const __attribute__((address_space(3))) char*)p;
}

// volatile asm ds_read_b128; readiness handled manually via counted lgkmcnt.
#define DSR(dst, ad, im)                                                     \
  asm volatile("ds_read_b128 %0, %1 offset:%c2"                              \
               : "=v"(dst) : "v"(ad), "i"(im))

// MFMA 2-k-step pair into one acc element
#define MM2(ACCE, X0, X1, Y0, Y1)                                            \
  ACCE = __builtin_amdgcn_mfma_f32_16x16x32_bf16(X0, Y0, ACCE, 0, 0, 0);     \
  ACCE = __builtin_amdgcn_mfma_f32_16x16x32_bf16(X1, Y1, ACCE, 0, 0, 0)

// ================= 256x256 8-phase bf16 GEMM: C = A(MxK) @ B(NxK)^T =========
// 512 thr = 8 waves (2M x 4N), per-wave 128x64 out, BK=64, LDS 128 KiB dbuf.
// LDS XOR swizzle byte ^= ((byte>>8)&3)<<5 via pre-swizzled global source +
// swizzled ds_read addresses (global_load_lds writes linearly).
// Pipelined schedule, tile u (window = before barrier, cluster = after):
//   P0: read aL,bl(u)[12] + STG_A(u+1,0) | Q3(u-1) aH x bh   (no lgkm wait)
//   P1: read bh(u)[4]     + STG_A(u+1,1) | Q0 aL x bl        lgkmcnt(4)
//   P2: read aH(u)[8]     + STG_B(u+2,0) | Q1 aL x bh        lgkmcnt(8)
//   P3:                     STG_B(u+2,1) | Q2 aH x bl        lgkmcnt(0)
//      + boundary vmcnt(4) (retires A(u+1),B(u+1); B(u+2) stays in flight)
// Final Q3(NT-1) after the loop. Same per-element accumulation order as the
// unpipelined version -> bitwise-identical output.
// EPI: 0 = fp32 out; 2 = bf16 out + per-128col-head Parseval normalize.
template <int EPI>
__global__ __launch_bounds__(512, 2) void gemm256(
    const u16* __restrict__ A, const u16* __restrict__ B, void* __restrict__ C,
    int N, int K) {
  __shared__ alignas(1024) char smem[131072];
  const int NT = K >> 6;            // K-tiles of 64 (requires NT>=3)
  const int ntn = N >> 8;
  const int nwg = gridDim.x;
  int wg = blockIdx.x;
  wg = (wg & 7) * (nwg >> 3) + (wg >> 3);   // XCD swizzle (nwg % 8 == 0)
  const int bm = wg / ntn, bn = wg % ntn;
  const long rowBase = (long)bm << 8, colBase = (long)bn << 8;

  const int tid = threadIdx.x;
  const int w = tid >> 6, lane = tid & 63;
  const int quad = lane >> 4, l16 = lane & 15;
  const int wm = w >> 2, wn = w & 3;

  // ---- staging addressing: linear LDS dest, pre-swizzled global source ----
  // one shared per-lane element offset; bases are wave-uniform (saddr form)
  const int grow = w * 8 + (lane >> 3);
  const int gcol = ((lane & 7) * 8) ^ ((lane >> 4) << 4);
  const long voff = (long)grow * K + gcol;       // per-lane, same for A and B
  const u16* Abase = A + rowBase * (long)K;      // uniform
  const u16* Bbase = B + colBase * (long)K;      // uniform
  char* ldsA = smem;            // [2 buf][256][64] bf16 = 64 KiB
  char* ldsB = smem + 65536;

#define STG_A(v, h)                                                          \
  do {                                                                       \
    char* d_ = ldsA + (((v)&1) << 15) + ((h) << 14) + (w << 10);             \
    GLD16(Abase + ((h) * 128L) * K + (long)(v) * 64 + voff, d_);             \
    GLD16(Abase + ((h) * 128L + 64) * K + (long)(v) * 64 + voff, d_ + 8192); \
  } while (0)
#define STG_B(v, h)                                                          \
  do {                                                                       \
    char* d_ = ldsB + (((v)&1) << 15) + ((h) << 14) + (w << 10);             \
    GLD16(Bbase + ((h) * 128L) * K + (long)(v) * 64 + voff, d_);             \
    GLD16(Bbase + ((h) * 128L + 64) * K + (long)(v) * 64 + voff, d_ + 8192); \
  } while (0)

  // ---- fragment read addressing (swizzled), 32-bit LDS byte addresses ----
  const int cb0 = (quad << 4) ^ (((l16 >> 1) & 3) << 5);
  const unsigned bA0 = ldsoff(ldsA + (wm * 128 + l16) * 128) + cb0;
  const unsigned bA1 = bA0 ^ 64;
  const unsigned bB0 = ldsoff(ldsB + (wn * 64 + l16) * 128) + cb0;
  const unsigned bB1 = bB0 ^ 64;

  short8 aL[8], aH[8], bl[4], bh[4];
  f32x4 acc[8][4] = {};

  // ---- prologue: A(0), B(0), B(1); keep B(1) (4 loads) in flight ----
  STG_A(0, 0); STG_A(0, 1); STG_B(0, 0); STG_B(0, 1);
  STG_B(1, 0); STG_B(1, 1);
  asm volatile("s_waitcnt vmcnt(4)");
  __builtin_amdgcn_s_barrier();

#define CLUSTER(BODY)                                                        \
  __builtin_amdgcn_sched_barrier(0);                                         \
  __builtin_amdgcn_s_setprio(1);                                             \
  BODY                                                                       \
  __builtin_amdgcn_s_setprio(0);                                             \
  __builtin_amdgcn_sched_barrier(0)

#define Q3P_BODY                                                             \
  _Pragma("unroll") for (int i = 0; i < 4; i++)                              \
    _Pragma("unroll") for (int j = 0; j < 2; j++) {                          \
      MM2(acc[i+4][j+2], aH[2*i], aH[2*i+1], bh[2*j], bh[2*j+1]);            \
    }
#define Q0_BODY                                                              \
  _Pragma("unroll") for (int i = 0; i < 4; i++)                              \
    _Pragma("unroll") for (int j = 0; j < 2; j++) {                          \
      MM2(acc[i][j], aL[2*i], aL[2*i+1], bl[2*j], bl[2*j+1]);                \
    }
#define Q1_BODY                                                              \
  _Pragma("unroll") for (int i = 0; i < 4; i++)                              \
    _Pragma("unroll") for (int j = 0; j < 2; j++) {                          \
      MM2(acc[i][j+2], aL[2*i], aL[2*i+1], bh[2*j], bh[2*j+1]);              \
    }
#define Q2_BODY                                                              \
  _Pragma("unroll") for (int i = 0; i < 4; i++)                              \
    _Pragma("unroll") for (int j = 0; j < 2; j++) {                          \
      MM2(acc[i+4][j], aH[2*i], aH[2*i+1], bl[2*j], bl[2*j+1]);              \
    }

#define RUN_TILE(uu, Q3P, SA_, SB_, WAITSTMT)                                \
  do {                                                                       \
    const unsigned bsel = ((uu) & 1) << 15;                                  \
    const unsigned aA0 = bA0 ^ bsel, aA1 = bA1 ^ bsel;                       \
    const unsigned aB0 = bB0 ^ bsel, aB1 = bB1 ^ bsel;                       \
    /* P0: read aL,bl; stage A(u+1)h0; cluster Q3(u-1) */                    \
    _Pragma("unroll") for (int i = 0; i < 4; i++) {                          \
      DSR(aL[2*i],   aA0, i * 2048);                                         \
      DSR(aL[2*i+1], aA1, i * 2048);                                         \
    }                                                                        \
    _Pragma("unroll") for (int j = 0; j < 2; j++) {                          \
      DSR(bl[2*j],   aB0, j * 2048);                                         \
      DSR(bl[2*j+1], aB1, j * 2048);                                         \
    }                                                                        \
    if (SA_) STG_A((uu) + 1, 0);                                             \
    __builtin_amdgcn_s_barrier();                                            \
    if (Q3P) { CLUSTER(Q3P_BODY); }                                          \
    __builtin_amdgcn_s_barrier();                                            \
    /* P1: read bh; stage A(u+1)h1; cluster Q0 (needs aL,bl: allow bh=4) */  \
    _Pragma("unroll") for (int j = 0; j < 2; j++) {                          \
      DSR(bh[2*j],   aB0, (j + 2) * 2048);                                   \
      DSR(bh[2*j+1], aB1, (j + 2) * 2048);                                   \
    }                                                                        \
    if (SA_) STG_A((uu) + 1, 1);                                             \
    __builtin_amdgcn_s_barrier();                                            \
    asm volatile("s_waitcnt lgkmcnt(4)");                                    \
    CLUSTER(Q0_BODY);                                                        \
    __builtin_amdgcn_s_barrier();                                            \
    /* P2: read aH; stage B(u+2)h0; cluster Q1 (needs bh: allow aH=8) */     \
    _Pragma("unroll") for (int i = 0; i < 4; i++) {                          \
      DSR(aH[2*i],   aA0, (i + 4) * 2048);                                   \
      DSR(aH[2*i+1], aA1, (i + 4) * 2048);                                   \
    }                                                                        \
    if (SB_) STG_B((uu) + 2, 0);                                             \
    __builtin_amdgcn_s_barrier();                                            \
    asm volatile("s_waitcnt lgkmcnt(8)");                                    \
    CLUSTER(Q1_BODY);                                                        \
    __builtin_amdgcn_s_barrier();                                            \
    /* P3: stage B(u+2)h1; cluster Q2 (needs aH: lgkmcnt(0)); boundary */    \
    if (SB_) STG_B((uu) + 2, 1);                                             \
    __builtin_amdgcn_s_barrier();                                            \
    asm volatile("s_waitcnt lgkmcnt(0)");                                    \
    CLUSTER(Q2_BODY);                                                        \
    WAITSTMT;                                                                \
    __builtin_amdgcn_s_barrier();                                            \
  } while (0)

  RUN_TILE(0, false, true, true, asm volatile("s_waitcnt vmcnt(4)"));
  for (int u = 1; u < NT - 2; ++u) {
    RUN_TILE(u, true, true, true, asm volatile("s_waitcnt vmcnt(4)"));
  }
  RUN_TILE(NT - 2, true, true, false, asm volatile("s_waitcnt vmcnt(0)"));
  RUN_TILE(NT - 1, true, false, false, (void)0);
  // final cluster: Q3 of the last tile (operands already lgkm-retired)
  { Q3P_BODY }
#undef RUN_TILE
#undef Q3P_BODY
#undef Q0_BODY
#undef Q1_BODY
#undef Q2_BODY
#undef CLUSTER
#undef STG_A
#undef STG_B

  // keep the GLD16 LDS writes live (asm reads are opaque) + order epilogue
  asm volatile("" ::: "memory");

  // ---- epilogue ----
  float scl[8][4];
#pragma unroll
  for (int i = 0; i < 8; i++)
#pragma unroll
    for (int r = 0; r < 4; r++) scl[i][r] = 1.0f;

  if (EPI == 2) {
    // per-head (128-col) Parseval normalize; wn pairs (0,1)/(2,3) share a
    // head; cross-wave reduce through LDS (pipeline fully drained above).
    float* ssb = (float*)smem;  // [256 rows][4 wn]
    __syncthreads();
#pragma unroll
    for (int i = 0; i < 8; i++)
#pragma unroll
      for (int r = 0; r < 4; r++) {
        float s = 0.f;
#pragma unroll
        for (int j = 0; j < 4; j++) { float v = acc[i][j][r]; s += v * v; }
        s += __shfl_xor(s, 1); s += __shfl_xor(s, 2);
        s += __shfl_xor(s, 4); s += __shfl_xor(s, 8);
        if (l16 == 0) ssb[((wm * 128 + i * 16 + quad * 4 + r) << 2) + wn] = s;
      }
    __syncthreads();
#pragma unroll
    for (int i = 0; i < 8; i++)
#pragma unroll
      for (int r = 0; r < 4; r++) {
        int row = wm * 128 + i * 16 + quad * 4 + r;
        float s = ssb[(row << 2) + (wn & 2)] + ssb[(row << 2) + (wn & 2) + 1];
        scl[i][r] = rsqrtf(128.0f * s);
      }
  }

  // C/D layout: col = lane&15, row = (lane>>4)*4 + reg  [verified m89/m91]
#pragma unroll
  for (int i = 0; i < 8; i++) {
#pragma unroll
    for (int j = 0; j < 4; j++) {
      long row0 = rowBase + wm * 128 + i * 16 + quad * 4;
      long col = colBase + wn * 64 + j * 16 + l16;
#pragma unroll
      for (int r = 0; r < 4; r++) {
        float v = acc[i][j][r] * scl[i][r];
        long off = (row0 + r) * (long)N + col;
        if (EPI == 0) ((float*)C)[off] = v;
        else          ((u16*)C)[off] = f2bf(v);
      }
    }
  }
}

// ---------------- bf16 GEMM (m97 128^2): C(MxN) = A(MxK) @ B(NxK)^T --------
// kept for the rDFT (N=128) and the small iDFT-fold GEMM.
template <int EPI, bool FOLD>
__global__ __launch_bounds__(256, 2) void gemm_bt(
    const u16* __restrict__ A, const u16* __restrict__ B, void* __restrict__ C,
    int M, int N, int K, int lda) {
  const int ntiles = N >> 7;
  const int bid = blockIdx.x;
  const int bm = bid / ntiles, bn = bid % ntiles;
  const long rowBase = (long)bm * 128, colBase = (long)bn * 128;
  const long aOff = FOLD ? colBase : 0;
  const long bRowBase = FOLD ? 0 : colBase;

  __shared__ u16 As[128 * 32];
  __shared__ u16 Bs[128 * 32];
  __shared__ float ssbuf[128][2];

  const int tid = threadIdx.x;
  const int wave = tid >> 6, lane = tid & 63;
  const int quad = lane >> 4, l16 = lane & 15;
  const int waveRow = (wave >> 1) * 64, waveCol = (wave & 1) * 64;

  const int srow = lane >> 2, scol = (lane & 3) * 8;
  const u16* pa = A + (rowBase + wave * 32 + srow) * (long)lda + aOff + scol;
  const u16* pb = B + (bRowBase + wave * 32 + srow) * (long)K + scol;
  u16* lA0 = &As[(wave * 32) * 32];
  u16* lA1 = &As[(wave * 32 + 16) * 32];
  u16* lB0 = &Bs[(wave * 32) * 32];
  u16* lB1 = &Bs[(wave * 32 + 16) * 32];

  f32x4 acc[4][4] = {};

  for (int kt = 0; kt < K; kt += 32) {
    GLD16(pa + kt, lA0);
    GLD16(pa + kt + 16 * (long)lda, lA1);
    GLD16(pb + kt, lB0);
    GLD16(pb + kt + 16 * (long)K, lB1);
    __syncthreads();

    short8 af[4], bfr[4];
#pragma unroll
    for (int i = 0; i < 4; i++)
      af[i] = *(const short8*)&As[(waveRow + i * 16 + l16) * 32 + quad * 8];
#pragma unroll
    for (int j = 0; j < 4; j++)
      bfr[j] = *(const short8*)&Bs[(waveCol + j * 16 + l16) * 32 + quad * 8];
#pragma unroll
    for (int i = 0; i < 4; i++)
#pragma unroll
      for (int j = 0; j < 4; j++)
        acc[i][j] = __builtin_amdgcn_mfma_f32_16x16x32_bf16(af[i], bfr[j], acc[i][j], 0, 0, 0);
    __syncthreads();
  }

  float scl[4][4];
#pragma unroll
  for (int i = 0; i < 4; i++)
#pragma unroll
    for (int r = 0; r < 4; r++) scl[i][r] = 1.0f;

  if (EPI == 2) {
#pragma unroll
    for (int i = 0; i < 4; i++) {
#pragma unroll
      for (int r = 0; r < 4; r++) {
        float s = 0.f;
#pragma unroll
        for (int j = 0; j < 4; j++) { float v = acc[i][j][r]; s += v * v; }
#pragma unroll
        for (int m = 1; m < 16; m <<= 1) s += __shfl_xor(s, m);
        if (l16 == 0) ssbuf[waveRow + i * 16 + quad * 4 + r][wave & 1] = s;
      }
    }
    __syncthreads();
#pragma unroll
    for (int i = 0; i < 4; i++)
#pragma unroll
      for (int r = 0; r < 4; r++) {
        int row = waveRow + i * 16 + quad * 4 + r;
        scl[i][r] = rsqrtf(128.0f * (ssbuf[row][0] + ssbuf[row][1]));
      }
  }

#pragma unroll
  for (int i = 0; i < 4; i++) {
#pragma unroll
    for (int j = 0; j < 4; j++) {
      long row0 = rowBase + waveRow + i * 16 + quad * 4;
      long col = colBase + waveCol + j * 16 + l16;
#pragma unroll
      for (int r = 0; r < 4; r++) {
        float v = acc[i][j][r] * scl[i][r];
        long off = (row0 + r) * (long)N + col;
        if (EPI == 0) ((float*)C)[off] = v;
        else          ((u16*)C)[off] = f2bf(v);
      }
    }
  }
}

// ---------------- fp32 -> bf16 cast (vectorized x4) ----------------
__global__ __launch_bounds__(256) void cast_f2b(const float* __restrict__ in,
                                                u16* __restrict__ out, int n4) {
  int i = blockIdx.x * 256 + threadIdx.x;
  if (i >= n4) return;
  float4 v = ((const float4*)in)[i];
  ushort4 u;
  u.x = f2bf(v.x); u.y = f2bf(v.y); u.z = f2bf(v.z); u.w = f2bf(v.w);
  ((ushort4*)out)[i] = u;
}

// ---------------- packed-rDFT matrices (bf16) ----------------
__global__ __launch_bounds__(256) void init_mats(u16* __restrict__ CSp,
                                                 u16* __restrict__ W2pT) {
  int idx = blockIdx.x * 256 + threadIdx.x;  // [0, 32768)
  const float PI64 = 3.14159265358979323846f / 64.0f;
  if (idx < 16384) {
    int p = idx >> 7, n = idx & 127;
    int k = p >> 1;
    float v;
    if (p == 1) v = (n & 1) ? -1.f : 1.f;
    else {
      int t = (k * n) & 127;
      float ang = (float)t * PI64;
      v = (p & 1) ? -sinf(ang) : cosf(ang);
    }
    CSp[p * 128 + n] = f2bf(v);
  } else {
    int r = idx - 16384;
    int p = r >> 7, d = r & 127;
    int k = p >> 1;
    float v;
    if (p == 0) v = 1.0f / 128.0f;
    else if (p == 1) v = ((d & 1) ? -1.f : 1.f) / 128.0f;
    else {
      int t = (k * d) & 127;
      float ang = (float)t * PI64;
      v = ((p & 1) ? -2.f * sinf(ang) : 2.f * cosf(ang)) / 128.0f;
    }
    W2pT[p * 128 + d] = f2bf(v);
  }
}

// ---------------- freq-domain causal cumsum (chunked scan, packed rows) -----
__global__ __launch_bounds__(64) void scan_chunksum(const u16* __restrict__ F,
                                                    float* __restrict__ part) {
  int blk = blockIdx.x;          // bh*64 + c
  int c = blk & 63, bh = blk >> 6;
  int h = bh & 15, b = bh >> 4;
  int l = threadIdx.x;           // 0..63
  float s0 = 0.f, s1 = 0.f;
  for (int t = c * 64; t < c * 64 + 64; ++t) {
    u32 u = ((const u32*)(F + ((long)(b * 4096 + t) * 32 + 16 + h) * 128))[l];
    s0 += bf2f((u16)(u & 0xffff));
    s1 += bf2f((u16)(u >> 16));
  }
  float2 w; w.x = s0; w.y = s1;
  ((float2*)part)[(long)blk * 64 + l] = w;
}

__global__ __launch_bounds__(128) void scan_exclusive(float* __restrict__ part) {
  int bh = blockIdx.x;   // 0..63
  int j = threadIdx.x;   // slot 0..127
  float run = 0.f;
  for (int c = 0; c < 64; ++c) {
    long idx = ((long)(bh * 64 + c)) * 128 + j;
    float v = part[idx];
    part[idx] = run;
    run += v;
  }
}

__global__ __launch_bounds__(64) void scan_main(const u16* __restrict__ F,
                                                u16* __restrict__ QV,
                                                const float* __restrict__ part) {
  int blk = blockIdx.x;          // bh*64 + c
  int c = blk & 63, bh = blk >> 6;
  int h = bh & 15, b = bh >> 4;
  int l = threadIdx.x;           // bin l
  float2 cc = ((const float2*)part)[(long)blk * 64 + l];
  float cr = cc.x, ci = cc.y;
  for (int t = c * 64; t < c * 64 + 64; ++t) {
    long m = (long)(b * 4096 + t);
    u32 ku = ((const u32*)(F + (m * 32 + 16 + h) * 128))[l];
    u32 qu = ((const u32*)(F + (m * 32 + h) * 128))[l];
    float kr = bf2f((u16)(ku & 0xffff)), ki = bf2f((u16)(ku >> 16));
    float qr = bf2f((u16)(qu & 0xffff)), qi = bf2f((u16)(qu >> 16));
    cr += kr; ci += ki;
    float vr, vi;
    if (l == 0) { vr = qr * cr; vi = qi * ci; }  // bins 0 and 64: pure real
    else { vr = qr * cr - qi * ci; vi = qr * ci + qi * cr; }
    ((u32*)(QV + (m * 16 + h) * 128))[l] = pack2(vr, vi);
  }
}

extern "C" void kernel_launch(void* const* d_in, const int* in_sizes, int n_in,
                              void* d_out, int out_size, void* d_ws, size_t ws_size,
                              hipStream_t stream) {
  const float* x   = (const float*)d_in[0];
  const float* Wq  = (const float*)d_in[1];
  const float* Wkv = (const float*)d_in[2];
  const float* Wo  = (const float*)d_in[3];
  float* out = (float*)d_out;

  const long M1 = 16384;          // B*S
  const long D = 2048;
  const long R = M1 * 16;         // 262144 head-rows
  const long XE = M1 * D;
  const long WE = D * D;

  char* ws = (char*)d_ws;
  u16* qkh  = (u16*)(ws);                         // 134 MB: GEMM1 out; QV reuses it
  u16* F    = (u16*)(ws + 134217728);             // 134 MB: packed DFT out (2R x 128)
  u16* xb   = (u16*)(ws + 268435456);             // 67 MB
  u16* wqkb = (u16*)(ws + 335544320);             // 16.8 MB: [Wq;Wkv]
  u16* wob  = (u16*)(ws + 352321536);             // 8.4 MB
  u16* wo2  = (u16*)(ws + 360710144);             // 8.4 MB: folded iDFT.Wo
  u16* CSp  = (u16*)(ws + 369098752);             // 32 KB
  u16* W2pT = (u16*)(ws + 369131520);             // 32 KB
  float* part = (float*)(ws + 369164288);         // 2 MB (64*64*128 f32)
  u16* QV = qkh;

  // casts + transform matrices
  cast_f2b<<<(int)(XE / 4 / 256), 256, 0, stream>>>(x, xb, (int)(XE / 4));
  cast_f2b<<<(int)(WE / 4 / 256), 256, 0, stream>>>(Wq, wqkb, (int)(WE / 4));
  cast_f2b<<<(int)(WE / 4 / 256), 256, 0, stream>>>(Wkv, wqkb + WE, (int)(WE / 4));
  cast_f2b<<<(int)(WE / 4 / 256), 256, 0, stream>>>(Wo, wob, (int)(WE / 4));
  init_mats<<<128, 256, 0, stream>>>(CSp, W2pT);

  // fold iDFT into Wo:  Wo2_h = Wo_h @ W2p  (block-diagonal, M=2048,N=2048,K=128)
  gemm_bt<1, true><<<16 * 16, 256, 0, stream>>>(wob, W2pT, wo2, 2048, 2048, 128, 2048);

  // qkv = x @ [Wq;Wkv]^T, fused per-head normalize (M=16384,N=4096,K=2048)
  gemm256<2><<<(int)((M1 / 256) * (4096 / 256)), 512, 0, stream>>>(
      xb, wqkb, qkh, 4096, (int)D);

  // packed rDFT: F = qkv_rows @ CSp^T  (M=2R, N=128, K=128)
  gemm_bt<1, false><<<(int)(2 * R / 128), 256, 0, stream>>>(
      qkh, CSp, F, (int)(2 * R), 128, 128, 128);

  // chunked causal cumsum + complex multiply -> QV (packed, into qkh)
  scan_chunksum<<<64 * 64, 64, 0, stream>>>(F, part);
  scan_exclusive<<<64, 128, 0, stream>>>(part);
  scan_main<<<64 * 64, 64, 0, stream>>>(F, QV, part);

  // out = QV_flat @ Wo2^T  (fp32 out, M=16384,N=2048,K=2048; iDFT folded in)
  gemm256<0><<<(int)((M1 / 256) * (D / 256)), 512, 0, stream>>>(
      QV, wo2, out, (int)D, (int)D);
}

// Round 4
// 724.368 us; speedup vs baseline: 1.0210x; 1.0210x over previous
//
#include <hip/hip_runtime.h>
#include <hip/hip_bf16.h>

// HRR self-attention, real-arithmetic + Hermitian-packed restructure (round 7):
//   qkv = x @ [Wq;Wkv]^T  (bf16 MFMA GEMM, per-head L2-normalize fused; Parseval)
//   F   = qkv_rows(2R x 128) @ CSp^T  (packed rDFT-128 as GEMM, out 2R x 128)
//   freq-domain causal cumsum of KF + complex mult -> QV (67 MB, packed)
//   out = QV_flat @ Wo2^T  where Wo2 = Wo (.) blockdiag-iDFT  (folded on device)
// Round 7: BARRIER-LIGHT gemm256. Rounds 4-6 (8 barriers/K-tile, waves in
// lockstep) all measured ~5220 cyc/tile = MFMA pipe (2485) + LDS pipe
// (~2000) SERIALIZED: during read-windows the matrix pipe idles, during MFMA
// clusters the LDS pipe idles, because every wave is in the same segment.
// Fix: drop the per-phase barriers (they were scheduling glue, not
// correctness). Per tile: issue all 24 ds_reads, clusters gated by counted
// lgkmcnt(12/8/0); ONE mid-tile barrier before the B(u+2) stages (B(u+2)
// overwrites the B-region being read this tile; all waves past lgkmcnt(8)
// have retired their bl/bh reads); boundary vmcnt(4)+barrier. Waves free-run
// and skew, so one wave's MFMA overlaps another's LDS reads.

typedef unsigned short u16;
typedef unsigned int u32;
typedef __attribute__((ext_vector_type(8))) short short8;
typedef __attribute__((ext_vector_type(4))) float f32x4;

__device__ __forceinline__ float bf2f(u16 u) {
  u32 x = ((u32)u) << 16;
  float f; __builtin_memcpy(&f, &x, 4); return f;
}
__device__ __forceinline__ u16 f2bf(float f) {
  __hip_bfloat16 h = __float2bfloat16(f);
  u16 u; __builtin_memcpy(&u, &h, 2); return u;
}
__device__ __forceinline__ u32 pack2(float a, float b) {
  return (u32)f2bf(a) | ((u32)f2bf(b) << 16);
}

#define GLD16(gp, lp)                                                        \
  __builtin_amdgcn_global_load_lds(                                          \
      (const __attribute__((address_space(1))) void*)(gp),                   \
      (__attribute__((address_space(3))) void*)(lp), 16, 0, 0)

// LDS byte offset of a generic pointer derived from __shared__
__device__ __forceinline__ unsigned ldsoff(const void* p) {
  return (unsigned)(size_t)(const __attribute__((address_space(3))) char*)p;
}

// volatile asm ds_read_b128; readiness handled manually via counted lgkmcnt.
#define DSR(dst, ad, im)                                                     \
  asm volatile("ds_read_b128 %0, %1 offset:%c2"                              \
               : "=v"(dst) : "v"(ad), "i"(im))

// MFMA 2-k-step pair into one acc element
#define MM2(ACCE, X0, X1, Y0, Y1)                                            \
  ACCE = __builtin_amdgcn_mfma_f32_16x16x32_bf16(X0, Y0, ACCE, 0, 0, 0);     \
  ACCE = __builtin_amdgcn_mfma_f32_16x16x32_bf16(X1, Y1, ACCE, 0, 0, 0)

// ================= 256x256 barrier-light bf16 GEMM: C = A @ B^T =============
// 512 thr = 8 waves (2M x 4N), per-wave 128x64 out, BK=64, LDS 128 KiB dbuf.
// LDS XOR swizzle byte ^= ((byte>>8)&3)<<5 via pre-swizzled global source +
// swizzled ds_read addresses (global_load_lds writes linearly).
// Tile u: [24 ds_reads][STG_A(u+1)] Q0@lgkm12 Q1@lgkm8 | mid-barrier |
//         [STG_B(u+2)] Q2,Q3@lgkm0 | vmcnt(4) | boundary barrier.
// vmcnt(4) at the boundary retires A(u+1) (B(u+2)'s 4 loads stay in flight).
// EPI: 0 = fp32 out; 2 = bf16 out + per-128col-head Parseval normalize.
template <int EPI>
__global__ __launch_bounds__(512, 2) void gemm256(
    const u16* __restrict__ A, const u16* __restrict__ B, void* __restrict__ C,
    int N, int K) {
  __shared__ alignas(1024) char smem[131072];
  const int NT = K >> 6;            // K-tiles of 64 (requires NT>=3)
  const int ntn = N >> 8;
  const int nwg = gridDim.x;
  int wg = blockIdx.x;
  wg = (wg & 7) * (nwg >> 3) + (wg >> 3);   // XCD swizzle (nwg % 8 == 0)
  const int bm = wg / ntn, bn = wg % ntn;
  const long rowBase = (long)bm << 8, colBase = (long)bn << 8;

  const int tid = threadIdx.x;
  const int w = tid >> 6, lane = tid & 63;
  const int quad = lane >> 4, l16 = lane & 15;
  const int wm = w >> 2, wn = w & 3;

  // ---- staging addressing: linear LDS dest, pre-swizzled global source ----
  const int grow = w * 8 + (lane >> 3);
  const int gcol = ((lane & 7) * 8) ^ ((lane >> 4) << 4);
  const long voff = (long)grow * K + gcol;       // per-lane, same for A and B
  const u16* Abase = A + rowBase * (long)K;      // uniform
  const u16* Bbase = B + colBase * (long)K;      // uniform
  char* ldsA = smem;            // [2 buf][256][64] bf16 = 64 KiB
  char* ldsB = smem + 65536;

#define STG_A(v, h)                                                          \
  do {                                                                       \
    char* d_ = ldsA + (((v)&1) << 15) + ((h) << 14) + (w << 10);             \
    GLD16(Abase + ((h) * 128L) * K + (long)(v) * 64 + voff, d_);             \
    GLD16(Abase + ((h) * 128L + 64) * K + (long)(v) * 64 + voff, d_ + 8192); \
  } while (0)
#define STG_B(v, h)                                                          \
  do {                                                                       \
    char* d_ = ldsB + (((v)&1) << 15) + ((h) << 14) + (w << 10);             \
    GLD16(Bbase + ((h) * 128L) * K + (long)(v) * 64 + voff, d_);             \
    GLD16(Bbase + ((h) * 128L + 64) * K + (long)(v) * 64 + voff, d_ + 8192); \
  } while (0)

  // ---- fragment read addressing (swizzled), 32-bit LDS byte addresses ----
  const int cb0 = (quad << 4) ^ (((l16 >> 1) & 3) << 5);
  const unsigned bA0 = ldsoff(ldsA + (wm * 128 + l16) * 128) + cb0;
  const unsigned bA1 = bA0 ^ 64;
  const unsigned bB0 = ldsoff(ldsB + (wn * 64 + l16) * 128) + cb0;
  const unsigned bB1 = bB0 ^ 64;

  short8 aL[8], aH[8], bl[4], bh[4];
  f32x4 acc[8][4] = {};

  // ---- prologue: A(0), B(0), B(1); keep B(1) (4 loads) in flight ----
  STG_A(0, 0); STG_A(0, 1); STG_B(0, 0); STG_B(0, 1);
  STG_B(1, 0); STG_B(1, 1);
  asm volatile("s_waitcnt vmcnt(4)");
  __builtin_amdgcn_s_barrier();
  __builtin_amdgcn_sched_barrier(0);

#define Q0_BODY                                                              \
  _Pragma("unroll") for (int i = 0; i < 4; i++)                              \
    _Pragma("unroll") for (int j = 0; j < 2; j++) {                          \
      MM2(acc[i][j], aL[2*i], aL[2*i+1], bl[2*j], bl[2*j+1]);                \
    }
#define Q1_BODY                                                              \
  _Pragma("unroll") for (int i = 0; i < 4; i++)                              \
    _Pragma("unroll") for (int j = 0; j < 2; j++) {                          \
      MM2(acc[i][j+2], aL[2*i], aL[2*i+1], bh[2*j], bh[2*j+1]);              \
    }
#define Q2_BODY                                                              \
  _Pragma("unroll") for (int i = 0; i < 4; i++)                              \
    _Pragma("unroll") for (int j = 0; j < 2; j++) {                          \
      MM2(acc[i+4][j], aH[2*i], aH[2*i+1], bl[2*j], bl[2*j+1]);              \
    }
#define Q3_BODY                                                              \
  _Pragma("unroll") for (int i = 0; i < 4; i++)                              \
    _Pragma("unroll") for (int j = 0; j < 2; j++) {                          \
      MM2(acc[i+4][j+2], aH[2*i], aH[2*i+1], bh[2*j], bh[2*j+1]);            \
    }

#define RUN_TILE(uu, SA_, SB_, WAITSTMT)                                     \
  do {                                                                       \
    const unsigned bsel = ((uu) & 1) << 15;                                  \
    const unsigned aA0 = bA0 ^ bsel, aA1 = bA1 ^ bsel;                       \
    const unsigned aB0 = bB0 ^ bsel, aB1 = bB1 ^ bsel;                       \
    /* issue ALL fragment reads: aL(8), bl(4), bh(4), aH(8) */               \
    _Pragma("unroll") for (int i = 0; i < 4; i++) {                          \
      DSR(aL[2*i],   aA0, i * 2048);                                         \
      DSR(aL[2*i+1], aA1, i * 2048);                                         \
    }                                                                        \
    _Pragma("unroll") for (int j = 0; j < 2; j++) {                          \
      DSR(bl[2*j],   aB0, j * 2048);                                         \
      DSR(bl[2*j+1], aB1, j * 2048);                                         \
    }                                                                        \
    _Pragma("unroll") for (int j = 0; j < 2; j++) {                          \
      DSR(bh[2*j],   aB0, (j + 2) * 2048);                                   \
      DSR(bh[2*j+1], aB1, (j + 2) * 2048);                                   \
    }                                                                        \
    _Pragma("unroll") for (int i = 0; i < 4; i++) {                          \
      DSR(aH[2*i],   aA0, (i + 4) * 2048);                                   \
      DSR(aH[2*i+1], aA1, (i + 4) * 2048);                                   \
    }                                                                        \
    if (SA_) { STG_A((uu) + 1, 0); STG_A((uu) + 1, 1); }                     \
    /* Q0 needs aL,bl: allow bh(4)+aH(8)=12 outstanding */                   \
    asm volatile("s_waitcnt lgkmcnt(12)");                                   \
    __builtin_amdgcn_sched_barrier(0);                                       \
    __builtin_amdgcn_s_setprio(1);                                           \
    Q0_BODY                                                                  \
    __builtin_amdgcn_s_setprio(0);                                           \
    /* Q1 needs bh: allow aH(8) outstanding */                               \
    asm volatile("s_waitcnt lgkmcnt(8)");                                    \
    __builtin_amdgcn_sched_barrier(0);                                       \
    __builtin_amdgcn_s_setprio(1);                                           \
    Q1_BODY                                                                  \
    __builtin_amdgcn_s_setprio(0);                                           \
    /* mid barrier: every wave past lgkmcnt(8) => all bl/bh reads retired, */\
    /* so B(u+2) may overwrite the B-region of buf[u&1] */                   \
    __builtin_amdgcn_s_barrier();                                            \
    __builtin_amdgcn_sched_barrier(0);                                       \
    if (SB_) { STG_B((uu) + 2, 0); STG_B((uu) + 2, 1); }                     \
    /* Q2,Q3 need aH */                                                      \
    asm volatile("s_waitcnt lgkmcnt(0)");                                    \
    __builtin_amdgcn_sched_barrier(0);                                       \
    __builtin_amdgcn_s_setprio(1);                                           \
    Q2_BODY                                                                  \
    Q3_BODY                                                                  \
    __builtin_amdgcn_s_setprio(0);                                           \
    WAITSTMT;                                                                \
    __builtin_amdgcn_s_barrier();                                            \
    __builtin_amdgcn_sched_barrier(0);                                       \
  } while (0)

  for (int u = 0; u < NT - 2; ++u) {
    RUN_TILE(u, true, true, asm volatile("s_waitcnt vmcnt(4)"));
  }
  RUN_TILE(NT - 2, true, false, asm volatile("s_waitcnt vmcnt(0)"));
  RUN_TILE(NT - 1, false, false, (void)0);
#undef RUN_TILE
#undef Q0_BODY
#undef Q1_BODY
#undef Q2_BODY
#undef Q3_BODY
#undef STG_A
#undef STG_B

  // keep the GLD16 LDS writes live (asm reads are opaque) + order epilogue
  asm volatile("" ::: "memory");

  // ---- epilogue ----
  float scl[8][4];
#pragma unroll
  for (int i = 0; i < 8; i++)
#pragma unroll
    for (int r = 0; r < 4; r++) scl[i][r] = 1.0f;

  if (EPI == 2) {
    // per-head (128-col) Parseval normalize; wn pairs (0,1)/(2,3) share a
    // head; cross-wave reduce through LDS (pipeline fully drained above).
    float* ssb = (float*)smem;  // [256 rows][4 wn]
    __syncthreads();
#pragma unroll
    for (int i = 0; i < 8; i++)
#pragma unroll
      for (int r = 0; r < 4; r++) {
        float s = 0.f;
#pragma unroll
        for (int j = 0; j < 4; j++) { float v = acc[i][j][r]; s += v * v; }
        s += __shfl_xor(s, 1); s += __shfl_xor(s, 2);
        s += __shfl_xor(s, 4); s += __shfl_xor(s, 8);
        if (l16 == 0) ssb[((wm * 128 + i * 16 + quad * 4 + r) << 2) + wn] = s;
      }
    __syncthreads();
#pragma unroll
    for (int i = 0; i < 8; i++)
#pragma unroll
      for (int r = 0; r < 4; r++) {
        int row = wm * 128 + i * 16 + quad * 4 + r;
        float s = ssb[(row << 2) + (wn & 2)] + ssb[(row << 2) + (wn & 2) + 1];
        scl[i][r] = rsqrtf(128.0f * s);
      }
  }

  // C/D layout: col = lane&15, row = (lane>>4)*4 + reg  [verified m89/m91]
#pragma unroll
  for (int i = 0; i < 8; i++) {
#pragma unroll
    for (int j = 0; j < 4; j++) {
      long row0 = rowBase + wm * 128 + i * 16 + quad * 4;
      long col = colBase + wn * 64 + j * 16 + l16;
#pragma unroll
      for (int r = 0; r < 4; r++) {
        float v = acc[i][j][r] * scl[i][r];
        long off = (row0 + r) * (long)N + col;
        if (EPI == 0) ((float*)C)[off] = v;
        else          ((u16*)C)[off] = f2bf(v);
      }
    }
  }
}

// ---------------- bf16 GEMM (m97 128^2): C(MxN) = A(MxK) @ B(NxK)^T --------
// kept for the rDFT (N=128) and the small iDFT-fold GEMM.
template <int EPI, bool FOLD>
__global__ __launch_bounds__(256, 2) void gemm_bt(
    const u16* __restrict__ A, const u16* __restrict__ B, void* __restrict__ C,
    int M, int N, int K, int lda) {
  const int ntiles = N >> 7;
  const int bid = blockIdx.x;
  const int bm = bid / ntiles, bn = bid % ntiles;
  const long rowBase = (long)bm * 128, colBase = (long)bn * 128;
  const long aOff = FOLD ? colBase : 0;
  const long bRowBase = FOLD ? 0 : colBase;

  __shared__ u16 As[128 * 32];
  __shared__ u16 Bs[128 * 32];
  __shared__ float ssbuf[128][2];

  const int tid = threadIdx.x;
  const int wave = tid >> 6, lane = tid & 63;
  const int quad = lane >> 4, l16 = lane & 15;
  const int waveRow = (wave >> 1) * 64, waveCol = (wave & 1) * 64;

  const int srow = lane >> 2, scol = (lane & 3) * 8;
  const u16* pa = A + (rowBase + wave * 32 + srow) * (long)lda + aOff + scol;
  const u16* pb = B + (bRowBase + wave * 32 + srow) * (long)K + scol;
  u16* lA0 = &As[(wave * 32) * 32];
  u16* lA1 = &As[(wave * 32 + 16) * 32];
  u16* lB0 = &Bs[(wave * 32) * 32];
  u16* lB1 = &Bs[(wave * 32 + 16) * 32];

  f32x4 acc[4][4] = {};

  for (int kt = 0; kt < K; kt += 32) {
    GLD16(pa + kt, lA0);
    GLD16(pa + kt + 16 * (long)lda, lA1);
    GLD16(pb + kt, lB0);
    GLD16(pb + kt + 16 * (long)K, lB1);
    __syncthreads();

    short8 af[4], bfr[4];
#pragma unroll
    for (int i = 0; i < 4; i++)
      af[i] = *(const short8*)&As[(waveRow + i * 16 + l16) * 32 + quad * 8];
#pragma unroll
    for (int j = 0; j < 4; j++)
      bfr[j] = *(const short8*)&Bs[(waveCol + j * 16 + l16) * 32 + quad * 8];
#pragma unroll
    for (int i = 0; i < 4; i++)
#pragma unroll
      for (int j = 0; j < 4; j++)
        acc[i][j] = __builtin_amdgcn_mfma_f32_16x16x32_bf16(af[i], bfr[j], acc[i][j], 0, 0, 0);
    __syncthreads();
  }

  float scl[4][4];
#pragma unroll
  for (int i = 0; i < 4; i++)
#pragma unroll
    for (int r = 0; r < 4; r++) scl[i][r] = 1.0f;

  if (EPI == 2) {
#pragma unroll
    for (int i = 0; i < 4; i++) {
#pragma unroll
      for (int r = 0; r < 4; r++) {
        float s = 0.f;
#pragma unroll
        for (int j = 0; j < 4; j++) { float v = acc[i][j][r]; s += v * v; }
#pragma unroll
        for (int m = 1; m < 16; m <<= 1) s += __shfl_xor(s, m);
        if (l16 == 0) ssbuf[waveRow + i * 16 + quad * 4 + r][wave & 1] = s;
      }
    }
    __syncthreads();
#pragma unroll
    for (int i = 0; i < 4; i++)
#pragma unroll
      for (int r = 0; r < 4; r++) {
        int row = waveRow + i * 16 + quad * 4 + r;
        scl[i][r] = rsqrtf(128.0f * (ssbuf[row][0] + ssbuf[row][1]));
      }
  }

#pragma unroll
  for (int i = 0; i < 4; i++) {
#pragma unroll
    for (int j = 0; j < 4; j++) {
      long row0 = rowBase + waveRow + i * 16 + quad * 4;
      long col = colBase + waveCol + j * 16 + l16;
#pragma unroll
      for (int r = 0; r < 4; r++) {
        float v = acc[i][j][r] * scl[i][r];
        long off = (row0 + r) * (long)N + col;
        if (EPI == 0) ((float*)C)[off] = v;
        else          ((u16*)C)[off] = f2bf(v);
      }
    }
  }
}

// ---------------- fp32 -> bf16 cast (vectorized x4) ----------------
__global__ __launch_bounds__(256) void cast_f2b(const float* __restrict__ in,
                                                u16* __restrict__ out, int n4) {
  int i = blockIdx.x * 256 + threadIdx.x;
  if (i >= n4) return;
  float4 v = ((const float4*)in)[i];
  ushort4 u;
  u.x = f2bf(v.x); u.y = f2bf(v.y); u.z = f2bf(v.z); u.w = f2bf(v.w);
  ((ushort4*)out)[i] = u;
}

// ---------------- packed-rDFT matrices (bf16) ----------------
__global__ __launch_bounds__(256) void init_mats(u16* __restrict__ CSp,
                                                 u16* __restrict__ W2pT) {
  int idx = blockIdx.x * 256 + threadIdx.x;  // [0, 32768)
  const float PI64 = 3.14159265358979323846f / 64.0f;
  if (idx < 16384) {
    int p = idx >> 7, n = idx & 127;
    int k = p >> 1;
    float v;
    if (p == 1) v = (n & 1) ? -1.f : 1.f;
    else {
      int t = (k * n) & 127;
      float ang = (float)t * PI64;
      v = (p & 1) ? -sinf(ang) : cosf(ang);
    }
    CSp[p * 128 + n] = f2bf(v);
  } else {
    int r = idx - 16384;
    int p = r >> 7, d = r & 127;
    int k = p >> 1;
    float v;
    if (p == 0) v = 1.0f / 128.0f;
    else if (p == 1) v = ((d & 1) ? -1.f : 1.f) / 128.0f;
    else {
      int t = (k * d) & 127;
      float ang = (float)t * PI64;
      v = ((p & 1) ? -2.f * sinf(ang) : 2.f * cosf(ang)) / 128.0f;
    }
    W2pT[p * 128 + d] = f2bf(v);
  }
}

// ---------------- freq-domain causal cumsum (chunked scan, packed rows) -----
__global__ __launch_bounds__(64) void scan_chunksum(const u16* __restrict__ F,
                                                    float* __restrict__ part) {
  int blk = blockIdx.x;          // bh*64 + c
  int c = blk & 63, bh = blk >> 6;
  int h = bh & 15, b = bh >> 4;
  int l = threadIdx.x;           // 0..63
  float s0 = 0.f, s1 = 0.f;
  for (int t = c * 64; t < c * 64 + 64; ++t) {
    u32 u = ((const u32*)(F + ((long)(b * 4096 + t) * 32 + 16 + h) * 128))[l];
    s0 += bf2f((u16)(u & 0xffff));
    s1 += bf2f((u16)(u >> 16));
  }
  float2 w; w.x = s0; w.y = s1;
  ((float2*)part)[(long)blk * 64 + l] = w;
}

__global__ __launch_bounds__(128) void scan_exclusive(float* __restrict__ part) {
  int bh = blockIdx.x;   // 0..63
  int j = threadIdx.x;   // slot 0..127
  float run = 0.f;
  for (int c = 0; c < 64; ++c) {
    long idx = ((long)(bh * 64 + c)) * 128 + j;
    float v = part[idx];
    part[idx] = run;
    run += v;
  }
}

__global__ __launch_bounds__(64) void scan_main(const u16* __restrict__ F,
                                                u16* __restrict__ QV,
                                                const float* __restrict__ part) {
  int blk = blockIdx.x;          // bh*64 + c
  int c = blk & 63, bh = blk >> 6;
  int h = bh & 15, b = bh >> 4;
  int l = threadIdx.x;           // bin l
  float2 cc = ((const float2*)part)[(long)blk * 64 + l];
  float cr = cc.x, ci = cc.y;
  for (int t = c * 64; t < c * 64 + 64; ++t) {
    long m = (long)(b * 4096 + t);
    u32 ku = ((const u32*)(F + (m * 32 + 16 + h) * 128))[l];
    u32 qu = ((const u32*)(F + (m * 32 + h) * 128))[l];
    float kr = bf2f((u16)(ku & 0xffff)), ki = bf2f((u16)(ku >> 16));
    float qr = bf2f((u16)(qu & 0xffff)), qi = bf2f((u16)(qu >> 16));
    cr += kr; ci += ki;
    float vr, vi;
    if (l == 0) { vr = qr * cr; vi = qi * ci; }  // bins 0 and 64: pure real
    else { vr = qr * cr - qi * ci; vi = qr * ci + qi * cr; }
    ((u32*)(QV + (m * 16 + h) * 128))[l] = pack2(vr, vi);
  }
}

extern "C" void kernel_launch(void* const* d_in, const int* in_sizes, int n_in,
                              void* d_out, int out_size, void* d_ws, size_t ws_size,
                              hipStream_t stream) {
  const float* x   = (const float*)d_in[0];
  const float* Wq  = (const float*)d_in[1];
  const float* Wkv = (const float*)d_in[2];
  const float* Wo  = (const float*)d_in[3];
  float* out = (float*)d_out;

  const long M1 = 16384;          // B*S
  const long D = 2048;
  const long R = M1 * 16;         // 262144 head-rows
  const long XE = M1 * D;
  const long WE = D * D;

  char* ws = (char*)d_ws;
  u16* qkh  = (u16*)(ws);                         // 134 MB: GEMM1 out; QV reuses it
  u16* F    = (u16*)(ws + 134217728);             // 134 MB: packed DFT out (2R x 128)
  u16* xb   = (u16*)(ws + 268435456);             // 67 MB
  u16* wqkb = (u16*)(ws + 335544320);             // 16.8 MB: [Wq;Wkv]
  u16* wob  = (u16*)(ws + 352321536);             // 8.4 MB
  u16* wo2  = (u16*)(ws + 360710144);             // 8.4 MB: folded iDFT.Wo
  u16* CSp  = (u16*)(ws + 369098752);             // 32 KB
  u16* W2pT = (u16*)(ws + 369131520);             // 32 KB
  float* part = (float*)(ws + 369164288);         // 2 MB (64*64*128 f32)
  u16* QV = qkh;

  // casts + transform matrices
  cast_f2b<<<(int)(XE / 4 / 256), 256, 0, stream>>>(x, xb, (int)(XE / 4));
  cast_f2b<<<(int)(WE / 4 / 256), 256, 0, stream>>>(Wq, wqkb, (int)(WE / 4));
  cast_f2b<<<(int)(WE / 4 / 256), 256, 0, stream>>>(Wkv, wqkb + WE, (int)(WE / 4));
  cast_f2b<<<(int)(WE / 4 / 256), 256, 0, stream>>>(Wo, wob, (int)(WE / 4));
  init_mats<<<128, 256, 0, stream>>>(CSp, W2pT);

  // fold iDFT into Wo:  Wo2_h = Wo_h @ W2p  (block-diagonal, M=2048,N=2048,K=128)
  gemm_bt<1, true><<<16 * 16, 256, 0, stream>>>(wob, W2pT, wo2, 2048, 2048, 128, 2048);

  // qkv = x @ [Wq;Wkv]^T, fused per-head normalize (M=16384,N=4096,K=2048)
  gemm256<2><<<(int)((M1 / 256) * (4096 / 256)), 512, 0, stream>>>(
      xb, wqkb, qkh, 4096, (int)D);

  // packed rDFT: F = qkv_rows @ CSp^T  (M=2R, N=128, K=128)
  gemm_bt<1, false><<<(int)(2 * R / 128), 256, 0, stream>>>(
      qkh, CSp, F, (int)(2 * R), 128, 128, 128);

  // chunked causal cumsum + complex multiply -> QV (packed, into qkh)
  scan_chunksum<<<64 * 64, 64, 0, stream>>>(F, part);
  scan_exclusive<<<64, 128, 0, stream>>>(part);
  scan_main<<<64 * 64, 64, 0, stream>>>(F, QV, part);

  // out = QV_flat @ Wo2^T  (fp32 out, M=16384,N=2048,K=2048; iDFT folded in)
  gemm256<0><<<(int)((M1 / 256) * (D / 256)), 512, 0, stream>>>(
      QV, wo2, out, (int)D, (int)D);
}

// Round 5
// 695.159 us; speedup vs baseline: 1.0639x; 1.0420x over previous
//
#include <hip/hip_runtime.h>
#include <hip/hip_bf16.h>

// HRR self-attention, real-arithmetic + Hermitian-packed restructure (round 8):
//   W2 = blockdiag(CSp) @ [Wq;Wkv]   (DFT folded into weights, one-shot)
//   F   = x @ W2^T  (bf16 MFMA GEMM; per-head Parseval normalize in epilogue)
//   freq-domain causal cumsum of KF + complex mult -> QV (67 MB, packed)
//   out = QV_flat @ Wo2^T  where Wo2 = Wo (.) blockdiag-iDFT  (folded on device)
// Round 8: the separate rDFT GEMM (read 134 MB qkh + write 134 MB F) is
// eliminated by pre-multiplying CSp into the qkv weights -- symmetric to the
// existing iDFT fold on Wo. The qkv GEMM now emits F directly (identical
// linear layout). Normalize moves to freq domain via Parseval on the packed
// row: scale = rsqrt(2*S - s0^2 - s1^2), S = row sumsq, s0/s1 = slots 0/1.
// gemm256 K-loop unchanged from round 7 (barrier-light, counted lgkmcnt).

typedef unsigned short u16;
typedef unsigned int u32;
typedef __attribute__((ext_vector_type(8))) short short8;
typedef __attribute__((ext_vector_type(4))) float f32x4;

__device__ __forceinline__ float bf2f(u16 u) {
  u32 x = ((u32)u) << 16;
  float f; __builtin_memcpy(&f, &x, 4); return f;
}
__device__ __forceinline__ u16 f2bf(float f) {
  __hip_bfloat16 h = __float2bfloat16(f);
  u16 u; __builtin_memcpy(&u, &h, 2); return u;
}
__device__ __forceinline__ u32 pack2(float a, float b) {
  return (u32)f2bf(a) | ((u32)f2bf(b) << 16);
}

#define GLD16(gp, lp)                                                        \
  __builtin_amdgcn_global_load_lds(                                          \
      (const __attribute__((address_space(1))) void*)(gp),                   \
      (__attribute__((address_space(3))) void*)(lp), 16, 0, 0)

__device__ __forceinline__ unsigned ldsoff(const void* p) {
  return (unsigned)(size_t)(const __attribute__((address_space(3))) char*)p;
}

#define DSR(dst, ad, im)                                                     \
  asm volatile("ds_read_b128 %0, %1 offset:%c2"                              \
               : "=v"(dst) : "v"(ad), "i"(im))

#define MM2(ACCE, X0, X1, Y0, Y1)                                            \
  ACCE = __builtin_amdgcn_mfma_f32_16x16x32_bf16(X0, Y0, ACCE, 0, 0, 0);     \
  ACCE = __builtin_amdgcn_mfma_f32_16x16x32_bf16(X1, Y1, ACCE, 0, 0, 0)

// ================= 256x256 barrier-light bf16 GEMM: C = A @ B^T =============
// 512 thr = 8 waves (2M x 4N), per-wave 128x64 out, BK=64, LDS 128 KiB dbuf.
// LDS XOR swizzle byte ^= ((byte>>8)&3)<<5 via pre-swizzled global source +
// swizzled ds_read addresses (global_load_lds writes linearly).
// Tile u: [24 ds_reads][STG_A(u+1)] Q0@lgkm12 Q1@lgkm8 | mid-barrier |
//         [STG_B(u+2)] Q2,Q3@lgkm0 | vmcnt(4) | boundary barrier.
// EPI: 0 = fp32 out; 2 = bf16 out + per-128col-head PARSEVAL normalize
//      (scale = rsqrt(2*S - s0^2 - s1^2) from the packed freq row).
template <int EPI>
__global__ __launch_bounds__(512, 2) void gemm256(
    const u16* __restrict__ A, const u16* __restrict__ B, void* __restrict__ C,
    int N, int K) {
  __shared__ alignas(1024) char smem[131072];
  const int NT = K >> 6;            // K-tiles of 64 (requires NT>=3)
  const int ntn = N >> 8;
  const int nwg = gridDim.x;
  int wg = blockIdx.x;
  wg = (wg & 7) * (nwg >> 3) + (wg >> 3);   // XCD swizzle (nwg % 8 == 0)
  const int bm = wg / ntn, bn = wg % ntn;
  const long rowBase = (long)bm << 8, colBase = (long)bn << 8;

  const int tid = threadIdx.x;
  const int w = tid >> 6, lane = tid & 63;
  const int quad = lane >> 4, l16 = lane & 15;
  const int wm = w >> 2, wn = w & 3;

  // ---- staging addressing: linear LDS dest, pre-swizzled global source ----
  const int grow = w * 8 + (lane >> 3);
  const int gcol = ((lane & 7) * 8) ^ ((lane >> 4) << 4);
  const long voff = (long)grow * K + gcol;       // per-lane, same for A and B
  const u16* Abase = A + rowBase * (long)K;      // uniform
  const u16* Bbase = B + colBase * (long)K;      // uniform
  char* ldsA = smem;            // [2 buf][256][64] bf16 = 64 KiB
  char* ldsB = smem + 65536;

#define STG_A(v, h)                                                          \
  do {                                                                       \
    char* d_ = ldsA + (((v)&1) << 15) + ((h) << 14) + (w << 10);             \
    GLD16(Abase + ((h) * 128L) * K + (long)(v) * 64 + voff, d_);             \
    GLD16(Abase + ((h) * 128L + 64) * K + (long)(v) * 64 + voff, d_ + 8192); \
  } while (0)
#define STG_B(v, h)                                                          \
  do {                                                                       \
    char* d_ = ldsB + (((v)&1) << 15) + ((h) << 14) + (w << 10);             \
    GLD16(Bbase + ((h) * 128L) * K + (long)(v) * 64 + voff, d_);             \
    GLD16(Bbase + ((h) * 128L + 64) * K + (long)(v) * 64 + voff, d_ + 8192); \
  } while (0)

  // ---- fragment read addressing (swizzled), 32-bit LDS byte addresses ----
  const int cb0 = (quad << 4) ^ (((l16 >> 1) & 3) << 5);
  const unsigned bA0 = ldsoff(ldsA + (wm * 128 + l16) * 128) + cb0;
  const unsigned bA1 = bA0 ^ 64;
  const unsigned bB0 = ldsoff(ldsB + (wn * 64 + l16) * 128) + cb0;
  const unsigned bB1 = bB0 ^ 64;

  short8 aL[8], aH[8], bl[4], bh[4];
  f32x4 acc[8][4] = {};

  // ---- prologue: A(0), B(0), B(1); keep B(1) (4 loads) in flight ----
  STG_A(0, 0); STG_A(0, 1); STG_B(0, 0); STG_B(0, 1);
  STG_B(1, 0); STG_B(1, 1);
  asm volatile("s_waitcnt vmcnt(4)");
  __builtin_amdgcn_s_barrier();
  __builtin_amdgcn_sched_barrier(0);

#define Q0_BODY                                                              \
  _Pragma("unroll") for (int i = 0; i < 4; i++)                              \
    _Pragma("unroll") for (int j = 0; j < 2; j++) {                          \
      MM2(acc[i][j], aL[2*i], aL[2*i+1], bl[2*j], bl[2*j+1]);                \
    }
#define Q1_BODY                                                              \
  _Pragma("unroll") for (int i = 0; i < 4; i++)                              \
    _Pragma("unroll") for (int j = 0; j < 2; j++) {                          \
      MM2(acc[i][j+2], aL[2*i], aL[2*i+1], bh[2*j], bh[2*j+1]);              \
    }
#define Q2_BODY                                                              \
  _Pragma("unroll") for (int i = 0; i < 4; i++)                              \
    _Pragma("unroll") for (int j = 0; j < 2; j++) {                          \
      MM2(acc[i+4][j], aH[2*i], aH[2*i+1], bl[2*j], bl[2*j+1]);              \
    }
#define Q3_BODY                                                              \
  _Pragma("unroll") for (int i = 0; i < 4; i++)                              \
    _Pragma("unroll") for (int j = 0; j < 2; j++) {                          \
      MM2(acc[i+4][j+2], aH[2*i], aH[2*i+1], bh[2*j], bh[2*j+1]);            \
    }

#define RUN_TILE(uu, SA_, SB_, WAITSTMT)                                     \
  do {                                                                       \
    const unsigned bsel = ((uu) & 1) << 15;                                  \
    const unsigned aA0 = bA0 ^ bsel, aA1 = bA1 ^ bsel;                       \
    const unsigned aB0 = bB0 ^ bsel, aB1 = bB1 ^ bsel;                       \
    _Pragma("unroll") for (int i = 0; i < 4; i++) {                          \
      DSR(aL[2*i],   aA0, i * 2048);                                         \
      DSR(aL[2*i+1], aA1, i * 2048);                                         \
    }                                                                        \
    _Pragma("unroll") for (int j = 0; j < 2; j++) {                          \
      DSR(bl[2*j],   aB0, j * 2048);                                         \
      DSR(bl[2*j+1], aB1, j * 2048);                                         \
    }                                                                        \
    _Pragma("unroll") for (int j = 0; j < 2; j++) {                          \
      DSR(bh[2*j],   aB0, (j + 2) * 2048);                                   \
      DSR(bh[2*j+1], aB1, (j + 2) * 2048);                                   \
    }                                                                        \
    _Pragma("unroll") for (int i = 0; i < 4; i++) {                          \
      DSR(aH[2*i],   aA0, (i + 4) * 2048);                                   \
      DSR(aH[2*i+1], aA1, (i + 4) * 2048);                                   \
    }                                                                        \
    if (SA_) { STG_A((uu) + 1, 0); STG_A((uu) + 1, 1); }                     \
    asm volatile("s_waitcnt lgkmcnt(12)");                                   \
    __builtin_amdgcn_sched_barrier(0);                                       \
    __builtin_amdgcn_s_setprio(1);                                           \
    Q0_BODY                                                                  \
    __builtin_amdgcn_s_setprio(0);                                           \
    asm volatile("s_waitcnt lgkmcnt(8)");                                    \
    __builtin_amdgcn_sched_barrier(0);                                       \
    __builtin_amdgcn_s_setprio(1);                                           \
    Q1_BODY                                                                  \
    __builtin_amdgcn_s_setprio(0);                                           \
    __builtin_amdgcn_s_barrier();                                            \
    __builtin_amdgcn_sched_barrier(0);                                       \
    if (SB_) { STG_B((uu) + 2, 0); STG_B((uu) + 2, 1); }                     \
    asm volatile("s_waitcnt lgkmcnt(0)");                                    \
    __builtin_amdgcn_sched_barrier(0);                                       \
    __builtin_amdgcn_s_setprio(1);                                           \
    Q2_BODY                                                                  \
    Q3_BODY                                                                  \
    __builtin_amdgcn_s_setprio(0);                                           \
    WAITSTMT;                                                                \
    __builtin_amdgcn_s_barrier();                                            \
    __builtin_amdgcn_sched_barrier(0);                                       \
  } while (0)

  for (int u = 0; u < NT - 2; ++u) {
    RUN_TILE(u, true, true, asm volatile("s_waitcnt vmcnt(4)"));
  }
  RUN_TILE(NT - 2, true, false, asm volatile("s_waitcnt vmcnt(0)"));
  RUN_TILE(NT - 1, false, false, (void)0);
#undef RUN_TILE
#undef Q0_BODY
#undef Q1_BODY
#undef Q2_BODY
#undef Q3_BODY
#undef STG_A
#undef STG_B

  // keep the GLD16 LDS writes live (asm reads are opaque) + order epilogue
  asm volatile("" ::: "memory");

  // ---- epilogue ----
  float scl[8][4];
#pragma unroll
  for (int i = 0; i < 8; i++)
#pragma unroll
    for (int r = 0; r < 4; r++) scl[i][r] = 1.0f;

  if (EPI == 2) {
    // Per-head (128-col) Parseval normalize from the PACKED freq row:
    // full-spectrum sumsq = 2*S - s0^2 - s1^2  (S = row sumsq over 128 slots,
    // s0 = re_0 at head-col 0, s1 = re_64 at head-col 1).
    // Head = wn pair (0,1)/(2,3); slots 0,1 live in waves wn=0/2, j=0, l16<2.
    float* ssb = (float*)smem;  // [256 rows][8]: 0-3 = wn sumsq, 4-5 = extra
    __syncthreads();
#pragma unroll
    for (int i = 0; i < 8; i++)
#pragma unroll
      for (int r = 0; r < 4; r++) {
        float s = 0.f;
#pragma unroll
        for (int j = 0; j < 4; j++) { float v = acc[i][j][r]; s += v * v; }
        float e = (l16 < 2) ? acc[i][0][r] * acc[i][0][r] : 0.f;
        s += __shfl_xor(s, 1); e += __shfl_xor(e, 1);
        s += __shfl_xor(s, 2); e += __shfl_xor(e, 2);
        s += __shfl_xor(s, 4); e += __shfl_xor(e, 4);
        s += __shfl_xor(s, 8); e += __shfl_xor(e, 8);
        int row = wm * 128 + i * 16 + quad * 4 + r;
        if (l16 == 0) {
          ssb[(row << 3) + wn] = s;
          if (!(wn & 1)) ssb[(row << 3) + 4 + (wn >> 1)] = e;
        }
      }
    __syncthreads();
#pragma unroll
    for (int i = 0; i < 8; i++)
#pragma unroll
      for (int r = 0; r < 4; r++) {
        int row = wm * 128 + i * 16 + quad * 4 + r;
        float S = ssb[(row << 3) + (wn & 2)] + ssb[(row << 3) + (wn & 2) + 1];
        float E = ssb[(row << 3) + 4 + (wn >> 1)];
        scl[i][r] = rsqrtf(2.0f * S - E);
      }
  }

  // C/D layout: col = lane&15, row = (lane>>4)*4 + reg  [verified m89/m91]
#pragma unroll
  for (int i = 0; i < 8; i++) {
#pragma unroll
    for (int j = 0; j < 4; j++) {
      long row0 = rowBase + wm * 128 + i * 16 + quad * 4;
      long col = colBase + wn * 64 + j * 16 + l16;
#pragma unroll
      for (int r = 0; r < 4; r++) {
        float v = acc[i][j][r] * scl[i][r];
        long off = (row0 + r) * (long)N + col;
        if (EPI == 0) ((float*)C)[off] = v;
        else          ((u16*)C)[off] = f2bf(v);
      }
    }
  }
}

// ---------------- bf16 GEMM (m97 128^2): C(MxN) = A(MxK) @ B(NxK)^T --------
// kept for the one-shot weight folds. TSTORE: write C transposed (C[col][row],
// row-major [N][M]) -- used to produce W2 = (CSp @ Wqkv) in [4096][2048].
template <int EPI, bool FOLD, bool TSTORE>
__global__ __launch_bounds__(256, 2) void gemm_bt(
    const u16* __restrict__ A, const u16* __restrict__ B, void* __restrict__ C,
    int M, int N, int K, int lda) {
  const int ntiles = N >> 7;
  const int bid = blockIdx.x;
  const int bm = bid / ntiles, bn = bid % ntiles;
  const long rowBase = (long)bm * 128, colBase = (long)bn * 128;
  const long aOff = FOLD ? colBase : 0;
  const long bRowBase = FOLD ? 0 : colBase;

  __shared__ u16 As[128 * 32];
  __shared__ u16 Bs[128 * 32];
  __shared__ float ssbuf[128][2];

  const int tid = threadIdx.x;
  const int wave = tid >> 6, lane = tid & 63;
  const int quad = lane >> 4, l16 = lane & 15;
  const int waveRow = (wave >> 1) * 64, waveCol = (wave & 1) * 64;

  const int srow = lane >> 2, scol = (lane & 3) * 8;
  const u16* pa = A + (rowBase + wave * 32 + srow) * (long)lda + aOff + scol;
  const u16* pb = B + (bRowBase + wave * 32 + srow) * (long)K + scol;
  u16* lA0 = &As[(wave * 32) * 32];
  u16* lA1 = &As[(wave * 32 + 16) * 32];
  u16* lB0 = &Bs[(wave * 32) * 32];
  u16* lB1 = &Bs[(wave * 32 + 16) * 32];

  f32x4 acc[4][4] = {};

  for (int kt = 0; kt < K; kt += 32) {
    GLD16(pa + kt, lA0);
    GLD16(pa + kt + 16 * (long)lda, lA1);
    GLD16(pb + kt, lB0);
    GLD16(pb + kt + 16 * (long)K, lB1);
    __syncthreads();

    short8 af[4], bfr[4];
#pragma unroll
    for (int i = 0; i < 4; i++)
      af[i] = *(const short8*)&As[(waveRow + i * 16 + l16) * 32 + quad * 8];
#pragma unroll
    for (int j = 0; j < 4; j++)
      bfr[j] = *(const short8*)&Bs[(waveCol + j * 16 + l16) * 32 + quad * 8];
#pragma unroll
    for (int i = 0; i < 4; i++)
#pragma unroll
      for (int j = 0; j < 4; j++)
        acc[i][j] = __builtin_amdgcn_mfma_f32_16x16x32_bf16(af[i], bfr[j], acc[i][j], 0, 0, 0);
    __syncthreads();
  }

  float scl[4][4];
#pragma unroll
  for (int i = 0; i < 4; i++)
#pragma unroll
    for (int r = 0; r < 4; r++) scl[i][r] = 1.0f;

  if (EPI == 2) {
#pragma unroll
    for (int i = 0; i < 4; i++) {
#pragma unroll
      for (int r = 0; r < 4; r++) {
        float s = 0.f;
#pragma unroll
        for (int j = 0; j < 4; j++) { float v = acc[i][j][r]; s += v * v; }
#pragma unroll
        for (int m = 1; m < 16; m <<= 1) s += __shfl_xor(s, m);
        if (l16 == 0) ssbuf[waveRow + i * 16 + quad * 4 + r][wave & 1] = s;
      }
    }
    __syncthreads();
#pragma unroll
    for (int i = 0; i < 4; i++)
#pragma unroll
      for (int r = 0; r < 4; r++) {
        int row = waveRow + i * 16 + quad * 4 + r;
        scl[i][r] = rsqrtf(128.0f * (ssbuf[row][0] + ssbuf[row][1]));
      }
  }

#pragma unroll
  for (int i = 0; i < 4; i++) {
#pragma unroll
    for (int j = 0; j < 4; j++) {
      long row0 = rowBase + waveRow + i * 16 + quad * 4;
      long col = colBase + waveCol + j * 16 + l16;
      if (TSTORE) {
        // rows r..r+3 are contiguous at fixed col in [N][M] layout: 8B store
        uint2 v;
        v.x = pack2(acc[i][j][0] * scl[i][0], acc[i][j][1] * scl[i][1]);
        v.y = pack2(acc[i][j][2] * scl[i][2], acc[i][j][3] * scl[i][3]);
        *(uint2*)((u16*)C + col * (long)M + row0) = v;
      } else {
#pragma unroll
        for (int r = 0; r < 4; r++) {
          float v = acc[i][j][r] * scl[i][r];
          long off = (row0 + r) * (long)N + col;
          if (EPI == 0) ((float*)C)[off] = v;
          else          ((u16*)C)[off] = f2bf(v);
        }
      }
    }
  }
}

// ---------------- fp32 -> bf16 cast (vectorized x4) ----------------
__global__ __launch_bounds__(256) void cast_f2b(const float* __restrict__ in,
                                                u16* __restrict__ out, int n4) {
  int i = blockIdx.x * 256 + threadIdx.x;
  if (i >= n4) return;
  float4 v = ((const float4*)in)[i];
  ushort4 u;
  u.x = f2bf(v.x); u.y = f2bf(v.y); u.z = f2bf(v.z); u.w = f2bf(v.w);
  ((ushort4*)out)[i] = u;
}

// ---------------- fp32 -> bf16 TRANSPOSE cast (one-shot, 2048x2048) --------
// out[d][co + c] (bf16, ld 4096) = in[c][d] (fp32, [2048][2048])
__global__ __launch_bounds__(256) void castT(const float* __restrict__ in,
                                             u16* __restrict__ out, int co) {
  __shared__ u16 tile[64][72];
  const int bx = blockIdx.x & 31, by = blockIdx.x >> 5;  // c-tile, d-tile
  const int c0 = bx * 64, d0 = by * 64;
  const int t = threadIdx.x;
  const int rr = t >> 2, cc = (t & 3) * 16;
  const float* ip = in + (long)(c0 + rr) * 2048 + d0 + cc;
#pragma unroll
  for (int e = 0; e < 4; e++) {
    float4 v = ((const float4*)ip)[e];
    tile[rr][cc + e * 4 + 0] = f2bf(v.x);
    tile[rr][cc + e * 4 + 1] = f2bf(v.y);
    tile[rr][cc + e * 4 + 2] = f2bf(v.z);
    tile[rr][cc + e * 4 + 3] = f2bf(v.w);
  }
  __syncthreads();
  u32 wb[8];
#pragma unroll
  for (int e = 0; e < 8; e++)
    wb[e] = (u32)tile[cc + 2 * e][rr] | ((u32)tile[cc + 2 * e + 1][rr] << 16);
  u32* op = (u32*)(out + (long)(d0 + rr) * 4096 + co + c0 + cc);
#pragma unroll
  for (int e = 0; e < 8; e++) op[e] = wb[e];
}

// ---------------- packed-rDFT matrices (bf16) ----------------
__global__ __launch_bounds__(256) void init_mats(u16* __restrict__ CSp,
                                                 u16* __restrict__ W2pT) {
  int idx = blockIdx.x * 256 + threadIdx.x;  // [0, 32768)
  const float PI64 = 3.14159265358979323846f / 64.0f;
  if (idx < 16384) {
    int p = idx >> 7, n = idx & 127;
    int k = p >> 1;
    float v;
    if (p == 1) v = (n & 1) ? -1.f : 1.f;
    else {
      int t = (k * n) & 127;
      float ang = (float)t * PI64;
      v = (p & 1) ? -sinf(ang) : cosf(ang);
    }
    CSp[p * 128 + n] = f2bf(v);
  } else {
    int r = idx - 16384;
    int p = r >> 7, d = r & 127;
    int k = p >> 1;
    float v;
    if (p == 0) v = 1.0f / 128.0f;
    else if (p == 1) v = ((d & 1) ? -1.f : 1.f) / 128.0f;
    else {
      int t = (k * d) & 127;
      float ang = (float)t * PI64;
      v = ((p & 1) ? -2.f * sinf(ang) : 2.f * cosf(ang)) / 128.0f;
    }
    W2pT[p * 128 + d] = f2bf(v);
  }
}

// ---------------- freq-domain causal cumsum (chunked scan, packed rows) -----
__global__ __launch_bounds__(64) void scan_chunksum(const u16* __restrict__ F,
                                                    float* __restrict__ part) {
  int blk = blockIdx.x;          // bh*64 + c
  int c = blk & 63, bh = blk >> 6;
  int h = bh & 15, b = bh >> 4;
  int l = threadIdx.x;           // 0..63
  float s0 = 0.f, s1 = 0.f;
#pragma unroll 8
  for (int t = c * 64; t < c * 64 + 64; ++t) {
    u32 u = ((const u32*)(F + ((long)(b * 4096 + t) * 32 + 16 + h) * 128))[l];
    s0 += bf2f((u16)(u & 0xffff));
    s1 += bf2f((u16)(u >> 16));
  }
  float2 w; w.x = s0; w.y = s1;
  ((float2*)part)[(long)blk * 64 + l] = w;
}

__global__ __launch_bounds__(128) void scan_exclusive(float* __restrict__ part) {
  int bh = blockIdx.x;   // 0..63
  int j = threadIdx.x;   // slot 0..127
  float run = 0.f;
  for (int c = 0; c < 64; ++c) {
    long idx = ((long)(bh * 64 + c)) * 128 + j;
    float v = part[idx];
    part[idx] = run;
    run += v;
  }
}

__global__ __launch_bounds__(64) void scan_main(const u16* __restrict__ F,
                                                u16* __restrict__ QV,
                                                const float* __restrict__ part) {
  int blk = blockIdx.x;          // bh*64 + c
  int c = blk & 63, bh = blk >> 6;
  int h = bh & 15, b = bh >> 4;
  int l = threadIdx.x;           // bin l
  float2 cc = ((const float2*)part)[(long)blk * 64 + l];
  float cr = cc.x, ci = cc.y;
#pragma unroll 4
  for (int t = c * 64; t < c * 64 + 64; ++t) {
    long m = (long)(b * 4096 + t);
    u32 ku = ((const u32*)(F + (m * 32 + 16 + h) * 128))[l];
    u32 qu = ((const u32*)(F + (m * 32 + h) * 128))[l];
    float kr = bf2f((u16)(ku & 0xffff)), ki = bf2f((u16)(ku >> 16));
    float qr = bf2f((u16)(qu & 0xffff)), qi = bf2f((u16)(qu >> 16));
    cr += kr; ci += ki;
    float vr, vi;
    if (l == 0) { vr = qr * cr; vi = qi * ci; }  // bins 0 and 64: pure real
    else { vr = qr * cr - qi * ci; vi = qr * ci + qi * cr; }
    ((u32*)(QV + (m * 16 + h) * 128))[l] = pack2(vr, vi);
  }
}

extern "C" void kernel_launch(void* const* d_in, const int* in_sizes, int n_in,
                              void* d_out, int out_size, void* d_ws, size_t ws_size,
                              hipStream_t stream) {
  const float* x   = (const float*)d_in[0];
  const float* Wq  = (const float*)d_in[1];
  const float* Wkv = (const float*)d_in[2];
  const float* Wo  = (const float*)d_in[3];
  float* out = (float*)d_out;

  const long M1 = 16384;          // B*S
  const long D = 2048;
  const long XE = M1 * D;
  const long WE = D * D;

  char* ws = (char*)d_ws;
  u16* w2   = (u16*)(ws);                         // 33.6 MB: folded DFT.Wqkv [4096][2048]
                                                  //   (later aliased by QV, 67 MB)
  u16* F    = (u16*)(ws + 134217728);             // 134 MB: packed freq out (16384 x 4096)
  u16* xb   = (u16*)(ws + 268435456);             // 67 MB
  u16* wqkT = (u16*)(ws + 335544320);             // 16.8 MB: [Wq;Wkv]^T  [2048][4096]
  u16* wob  = (u16*)(ws + 352321536);             // 8.4 MB
  u16* wo2  = (u16*)(ws + 360710144);             // 8.4 MB: folded iDFT.Wo
  u16* CSp  = (u16*)(ws + 369098752);             // 32 KB
  u16* W2pT = (u16*)(ws + 369131520);             // 32 KB
  float* part = (float*)(ws + 369164288);         // 2 MB (64*64*128 f32)
  u16* QV = (u16*)(ws);                           // 67 MB, after w2 is dead

  // casts + transform matrices
  cast_f2b<<<(int)(XE / 4 / 256), 256, 0, stream>>>(x, xb, (int)(XE / 4));
  castT<<<1024, 256, 0, stream>>>(Wq, wqkT, 0);
  castT<<<1024, 256, 0, stream>>>(Wkv, wqkT, 2048);
  cast_f2b<<<(int)(WE / 4 / 256), 256, 0, stream>>>(Wo, wob, (int)(WE / 4));
  init_mats<<<128, 256, 0, stream>>>(CSp, W2pT);

  // fold iDFT into Wo:  Wo2_h = Wo_h @ W2p  (block-diagonal, M=2048,N=2048,K=128)
  gemm_bt<1, true, false><<<16 * 16, 256, 0, stream>>>(
      wob, W2pT, wo2, 2048, 2048, 128, 2048);

  // fold DFT into Wqkv: W2[c][d] = sum_n CSp[p][n] * Wqkv[j*128+n][d]
  // computed as W2T = wqkT @ blockdiag(CSp)^T, stored transposed (TSTORE)
  gemm_bt<1, true, true><<<16 * 32, 256, 0, stream>>>(
      wqkT, CSp, w2, 2048, 4096, 128, 4096);

  // F = x @ W2^T directly (M=16384,N=4096,K=2048), per-head Parseval
  // normalize in the epilogue. Same linear layout as the old rDFT output.
  gemm256<2><<<(int)((M1 / 256) * (4096 / 256)), 512, 0, stream>>>(
      xb, w2, F, 4096, (int)D);

  // chunked causal cumsum + complex multiply -> QV (packed, over w2's region)
  scan_chunksum<<<64 * 64, 64, 0, stream>>>(F, part);
  scan_exclusive<<<64, 128, 0, stream>>>(part);
  scan_main<<<64 * 64, 64, 0, stream>>>(F, QV, part);

  // out = QV_flat @ Wo2^T  (fp32 out, M=16384,N=2048,K=2048; iDFT folded in)
  gemm256<0><<<(int)((M1 / 256) * (D / 256)), 512, 0, stream>>>(
      QV, wo2, out, (int)D, (int)D);
}